// Round 8
// baseline (417.213 us; speedup 1.0000x reference)
//
#include <hip/hip_runtime.h>
#include <cstdint>
#include <cstddef>

#define Bn 8
#define Cn 64
#define HWn 65536

// ws float offsets
#define WS_Z 0
#define WS_XPOOL 8
#define WS_A 520
#define WS_WA 1032
#define WS_M1 1544
#define WS_M2 5640
#define WS_S 38408   // 8*65536 floats; 16B aligned (38408%4==0)

// NOTE: M1/M2 in ws are stored TRANSPOSED: element [c][o] at dst[c*64+o]
// (so k4f can scalar-load 16 contiguous output-weights per input channel).
//
// k4f LESSONS (R3-R5, do not retry):
//  - __launch_bounds__(256,3) + explicit 2-bank pipeline -> acc spills to scratch
//    (VGPR 84, WRITE 887MB, 574us).
//  - __builtin_nontemporal_store(*(f32x4*)&acc[o], ...) -> address-taken acc array
//    defeats SROA, acc lives in scratch (WRITE 4.2GB, 1309us).
//  - Verified optimum: scalar SGPR weights, unroll 4, (256,4), plain float4 stores,
//    acc in AGPRs (VGPR_Count 60) -> 137us.
//
// R7 accounting: k1 ~122us, k3 ~134us (~1.1 TB/s each). R0-k4f proved the same
// stride pattern streams at 2.55 TB/s with 4 blocks/CU + interleaved compute ->
// k1/k3 wall = per-CU load concurrency, not DRAM.
// R8 experiment: k3 channel-split (32ch/block, grid 1024 = 4 blocks/CU), partials
// to planes (b,2)+(b,3), kconv sums them. k1/k4f untouched.

// K1 single-pass: e = exp(Wk.x); Z[b] += sum(e); xpool[b,c] += sum_n x*e
// grid 1024 (b * 128 tiles of 512 px), 256 threads, 2 px/thread (float2).
__global__ __launch_bounds__(256) void k1(const float* __restrict__ x, const float* __restrict__ Wk,
                                          float* __restrict__ ws) {
  __shared__ float zred[4];
  __shared__ float cpart[4][64];
  int blk = blockIdx.x;
  int b = blk >> 7;
  int base = (blk & 127) << 9;
  int t = threadIdx.x;
  int lane = t & 63, wid = t >> 6;
  const float* xb = x + (size_t)b * Cn * HWn;
  int n0 = base + t * 2;

  float2 xv[64];
  float kx = 0.f, ky = 0.f;
#pragma unroll
  for (int c = 0; c < Cn; ++c) {
    xv[c] = *(const float2*)(xb + (size_t)c * HWn + n0);
    float w = Wk[c];
    kx += w * xv[c].x; ky += w * xv[c].y;
  }
  float ex = __expf(kx), ey = __expf(ky);

  // Z partial
  float part = ex + ey;
#pragma unroll
  for (int off = 32; off; off >>= 1) part += __shfl_down(part, off, 64);
  if (lane == 0) zred[wid] = part;

  // per-channel partials, in-register (x NOT re-read)
#pragma unroll
  for (int c = 0; c < Cn; ++c) {
    float pc = xv[c].x * ex + xv[c].y * ey;
#pragma unroll
    for (int off = 32; off; off >>= 1) pc += __shfl_down(pc, off, 64);
    if (lane == 0) cpart[wid][c] = pc;
  }
  __syncthreads();
  if (t == 0) atomicAdd(&ws[WS_Z + b], zred[0] + zred[1] + zred[2] + zred[3]);
  if (t < 64) {
    float s = cpart[0][t] + cpart[1][t] + cpart[2][t] + cpart[3][t];
    atomicAdd(&ws[WS_XPOOL + b * 64 + t], s);
  }
}

// K2a: per-batch a = softmax(Wup @ Wq @ (xpool/Z)); wa = Wq^T a
// grid 8 (one block per batch), 64 threads, fully unrolled dot products
__global__ void k2a(const float* __restrict__ Wq, const float* __restrict__ Wup, float* __restrict__ ws) {
  int b = blockIdx.x;
  int t = threadIdx.x;  // 0..63
  __shared__ float xp_s[64], t1[64], a_s[64];
  float Zb = ws[WS_Z + b];
  xp_s[t] = ws[WS_XPOOL + b * 64 + t] / Zb;
  __syncthreads();
  float acc = 0.f;
#pragma unroll
  for (int i = 0; i < 64; ++i) acc += Wq[t * 64 + i] * xp_s[i];
  t1[t] = acc;
  __syncthreads();
  float acc2 = 0.f;
#pragma unroll
  for (int i = 0; i < 64; ++i) acc2 += Wup[t * 64 + i] * t1[i];
  float m = acc2;
#pragma unroll
  for (int off = 32; off; off >>= 1) m = fmaxf(m, __shfl_xor(m, off, 64));
  float e = __expf(acc2 - m);
  float ssum = e;
#pragma unroll
  for (int off = 32; off; off >>= 1) ssum += __shfl_xor(ssum, off, 64);
  float av = e / ssum;
  ws[WS_A + b * 64 + t] = av;
  a_s[t] = av;
  __syncthreads();
  float wav = 0.f;
#pragma unroll
  for (int o = 0; o < 64; ++o) wav += a_s[o] * Wq[o * 64 + t];
  ws[WS_WA + b * 64 + t] = wav;
}

// K2b: block 0 -> M1 = Wout@Wv_spa ; block j=1..8 -> M2[b=j-1] = Wout@diag(a[b])@Wv_spe
// Stores TRANSPOSED: dst[c*64+o] = M[o][c]
__global__ __launch_bounds__(256) void k2b(const float* __restrict__ Wout, const float* __restrict__ Wv_spa,
                                           const float* __restrict__ Wv_spe, float* __restrict__ ws) {
  __shared__ float A[4096], Bm[4096];
  int j = blockIdx.x;
  for (int idx = threadIdx.x; idx < 4096; idx += 256) {
    A[idx] = Wout[idx];
    if (j == 0)
      Bm[idx] = Wv_spa[idx];
    else
      Bm[idx] = ws[WS_A + (j - 1) * 64 + (idx >> 6)] * Wv_spe[idx];
  }
  __syncthreads();
  float* dst = (j == 0) ? (ws + WS_M1) : (ws + WS_M2 + (size_t)(j - 1) * 4096);
  for (int oi = threadIdx.x; oi < 4096; oi += 256) {
    int o = oi >> 6, i = oi & 63;
    float acc = 0.f;
#pragma unroll
    for (int c = 0; c < 64; ++c) acc += A[o * 64 + c] * Bm[c * 64 + i];
    dst[i * 64 + o] = acc;   // transposed store: [input c][output o]
  }
}

// K3 channel-split: partial attn_spa over 32 channels -> plane(b, 2+chg).
// grid 1024 = b(8) x chg(2) x tile(64); 1024 px/block, 4 px/thread (float4).
// 4 blocks/CU (vs 2 before) doubles resident waves issuing loads.
__global__ __launch_bounds__(256) void k3(const float* __restrict__ x, const float* __restrict__ ws,
                                          float* __restrict__ out) {
  int blk = blockIdx.x;
  int b = blk >> 7;
  int chg = (blk >> 6) & 1;
  int tile = blk & 63;
  int n0 = (tile << 10) + threadIdx.x * 4;
  const float* xb = x + ((size_t)b * Cn + chg * 32) * HWn;
  const float* wa = ws + WS_WA + b * 64 + chg * 32;
  float kx = 0.f, ky = 0.f, kz = 0.f, kw = 0.f;
#pragma unroll
  for (int c = 0; c < 32; ++c) {
    float4 xv = *(const float4*)(xb + (size_t)c * HWn + n0);
    float w = wa[c];
    kx += w * xv.x; ky += w * xv.y; kz += w * xv.z; kw += w * xv.w;
  }
  float4 r = {kx, ky, kz, kw};
  *(float4*)(out + ((size_t)(b * Cn + 2 + chg)) * HWn + n0) = r;
}

// Kconv: s = sigmoid(conv7x7(attn_spa)); attn_spa = plane(b,2) + plane(b,3)
// (k3 channel-split partials), write dst_base + b*dst_stride
__global__ __launch_bounds__(256) void kconv(const float* __restrict__ Wn, const float* __restrict__ out,
                                             float* __restrict__ dst_base, size_t dst_stride) {
  __shared__ float t[38 * 38];
  int blk = blockIdx.x;
  int b = blk >> 6, ty = (blk >> 3) & 7, tx = blk & 7;
  const float* src0 = out + ((size_t)(b * Cn + 2)) * HWn;
  const float* src1 = out + ((size_t)(b * Cn + 3)) * HWn;
  float* dstp = dst_base + (size_t)b * dst_stride;
  for (int idx = threadIdx.x; idx < 38 * 38; idx += 256) {
    int ly = idx / 38, lx = idx - ly * 38;
    int gy = ty * 32 + ly - 3, gx = tx * 32 + lx - 3;
    float v = 0.f;
    if (gy >= 0 && gy < 256 && gx >= 0 && gx < 256) {
      int g = gy * 256 + gx;
      v = src0[g] + src1[g];
    }
    t[idx] = v;
  }
  __syncthreads();
#pragma unroll
  for (int q = 0; q < 4; ++q) {
    int pix = threadIdx.x + q * 256;
    int r = pix >> 5, col = pix & 31;
    float acc = 0.f;
#pragma unroll
    for (int dy = 0; dy < 7; ++dy)
#pragma unroll
      for (int dx = 0; dx < 7; ++dx)
        acc += t[(r + dy) * 38 + (col + dx)] * Wn[dy * 7 + dx];
    float sg = 1.f / (1.f + __expf(-acc));
    dstp[(ty * 32 + r) * 256 + tx * 32 + col] = sg;
  }
}

// K4 fast (VERIFIED 137us config — do not restructure): grid 2048, XCD-group swizzle
// (4 oc-blocks of one (b,tile) share an XCD's L2). Weights wave-uniform -> scalar
// loads (SGPR); compiler keeps acc in AGPRs (unified RF). Plain float4 stores.
__global__ __launch_bounds__(256, 4) void k4f(const float* __restrict__ x, const float* __restrict__ ws,
                                              float* __restrict__ out) {
  int d = blockIdx.x;
  int xcd = d & 7;
  int j = d >> 3;          // 0..255
  int oc = j & 3;
  int pg = j >> 2;         // 0..63
  int p = pg * 8 + xcd;    // 0..511 = (b,tile), bijective
  int b = p >> 6;
  int tile = p & 63;
  int t = threadIdx.x;
  const float* m1t = ws + WS_M1 + oc * 16;                      // [c][o] rows of 64
  const float* m2t = ws + WS_M2 + (size_t)b * 4096 + oc * 16;

  int n0 = (tile << 10) + t * 4;
  const float* xb = x + (size_t)b * Cn * HWn;
  float4 s4 = *(const float4*)(ws + WS_S + (size_t)b * HWn + n0);
  float4 acc[16];
#pragma unroll
  for (int o = 0; o < 16; ++o) acc[o] = make_float4(0.f, 0.f, 0.f, 0.f);

#pragma unroll 4
  for (int i = 0; i < 64; ++i) {
    float4 xv = *(const float4*)(xb + (size_t)i * HWn + n0);
    float4 sx;
    sx.x = s4.x * xv.x; sx.y = s4.y * xv.y; sx.z = s4.z * xv.z; sx.w = s4.w * xv.w;
    const float* w1r = m1t + i * 64;   // uniform address -> s_load
    const float* w2r = m2t + i * 64;
#pragma unroll
    for (int o = 0; o < 16; ++o) {
      float w1 = w1r[o], w2 = w2r[o];
      acc[o].x += w1 * sx.x + w2 * xv.x;
      acc[o].y += w1 * sx.y + w2 * xv.y;
      acc[o].z += w1 * sx.z + w2 * xv.z;
      acc[o].w += w1 * sx.w + w2 * xv.w;
    }
  }
  float* op = out + ((size_t)(b * Cn + oc * 16)) * HWn + n0;
#pragma unroll
  for (int o = 0; o < 16; ++o)
    *(float4*)(op + (size_t)o * HWn) = acc[o];
}

// K4 mono fallback (ws too small for s buffer): oc loop in-block, s owner-read from plane(b,0)
// (M1/M2 arrive transposed [c][o]; LDS layout [c][o] with padded stride.)
#define MSTRIDE 68
__global__ __launch_bounds__(256) void k4m(const float* __restrict__ x, const float* __restrict__ ws,
                                           float* out) {
  __shared__ float M1T[64 * MSTRIDE];
  __shared__ float M2T[64 * MSTRIDE];
  int blk = blockIdx.x;
  int b = blk >> 6;
  int base = (blk & 63) << 10;
  int t = threadIdx.x;
  const float* m1g = ws + WS_M1;
  const float* m2g = ws + WS_M2 + (size_t)b * 4096;
  for (int idx = t; idx < 4096; idx += 256) {
    int c = idx >> 6, o = idx & 63;
    M1T[c * MSTRIDE + o] = m1g[idx];
    M2T[c * MSTRIDE + o] = m2g[idx];
  }
  __syncthreads();
  int n0 = base + t * 4;
  const float* xb = x + (size_t)b * Cn * HWn;
  float* op = out + ((size_t)(b * Cn)) * HWn + n0;
  float4 s4 = *(const float4*)op;
#pragma unroll
  for (int oc = 0; oc < 4; ++oc) {
    float4 acc[16];
#pragma unroll
    for (int o = 0; o < 16; ++o) acc[o] = make_float4(0.f, 0.f, 0.f, 0.f);
    for (int i = 0; i < 64; ++i) {
      float4 xv = *(const float4*)(xb + (size_t)i * HWn + n0);
      float4 sx;
      sx.x = s4.x * xv.x; sx.y = s4.y * xv.y; sx.z = s4.z * xv.z; sx.w = s4.w * xv.w;
      const float* m1r = M1T + i * MSTRIDE + oc * 16;
      const float* m2r = M2T + i * MSTRIDE + oc * 16;
#pragma unroll
      for (int o = 0; o < 16; ++o) {
        float m1 = m1r[o], m2 = m2r[o];
        acc[o].x += m1 * sx.x + m2 * xv.x;
        acc[o].y += m1 * sx.y + m2 * xv.y;
        acc[o].z += m1 * sx.z + m2 * xv.z;
        acc[o].w += m1 * sx.w + m2 * xv.w;
      }
    }
#pragma unroll
    for (int o = 0; o < 16; ++o)
      *(float4*)(op + (size_t)(oc * 16 + o) * HWn) = acc[o];
  }
}

extern "C" void kernel_launch(void* const* d_in, const int* in_sizes, int n_in,
                              void* d_out, int out_size, void* d_ws, size_t ws_size,
                              hipStream_t stream) {
  const float* x      = (const float*)d_in[0];
  const float* Wq     = (const float*)d_in[1];
  const float* Wk     = (const float*)d_in[2];
  const float* Wv_spe = (const float*)d_in[3];
  const float* Wv_spa = (const float*)d_in[4];
  const float* Wup    = (const float*)d_in[5];
  const float* Wout   = (const float*)d_in[6];
  const float* Wn     = (const float*)d_in[7];
  float* out = (float*)d_out;
  float* ws  = (float*)d_ws;

  bool fast = ws_size >= (size_t)(WS_S + Bn * HWn) * sizeof(float);

  (void)hipMemsetAsync(ws, 0, 520 * sizeof(float), stream);  // Z + xpool accumulators
  k1<<<1024, 256, 0, stream>>>(x, Wk, ws);
  k2a<<<8, 64, 0, stream>>>(Wq, Wup, ws);
  k2b<<<9, 256, 0, stream>>>(Wout, Wv_spa, Wv_spe, ws);
  k3<<<1024, 256, 0, stream>>>(x, ws, out);
  if (fast) {
    kconv<<<512, 256, 0, stream>>>(Wn, out, ws + WS_S, (size_t)HWn);
    k4f<<<2048, 256, 0, stream>>>(x, ws, out);
  } else {
    kconv<<<512, 256, 0, stream>>>(Wn, out, out, (size_t)Cn * HWn);
    k4m<<<512, 256, 0, stream>>>(x, ws, out);
  }
}

// Round 9
// 416.022 us; speedup vs baseline: 1.0029x; 1.0029x over previous
//
#include <hip/hip_runtime.h>
#include <cstdint>
#include <cstddef>

#define Bn 8
#define Cn 64
#define HWn 65536

// ws float offsets
#define WS_Z 0
#define WS_XPOOL 8
#define WS_A 520
#define WS_WA 1032
#define WS_M1 1544
#define WS_M2 5640
#define WS_S 38408   // 8*65536 floats; 16B aligned (38408%4==0)

// NOTE: M1/M2 in ws are stored TRANSPOSED: element [c][o] at dst[c*64+o]
// (so k4f can scalar-load 16 contiguous output-weights per input channel).
//
// k4f LESSONS (R3-R5, do not retry):
//  - __launch_bounds__(256,3) + explicit 2-bank pipeline -> acc spills to scratch.
//  - nontemporal_store of address-taken acc array -> scratch (WRITE 4.2GB).
//  - Verified optimum: scalar SGPR weights, unroll 4, (256,4), plain float4 stores -> 137us.
//
// Streaming-wall log (k1/k3 ~1.0-1.1 TB/s): flat across float2/float4, unroll 16/32,
// 2/4 blocks/CU (R1/R6/R8). R9 tests the last axis: 8 blocks/CU (32 waves/CU) via
// 16-channel partial sums + XCD-grouped tile runs; kconv sums 4 partial planes.

// K1 single-pass: e = exp(Wk.x); Z[b] += sum(e); xpool[b,c] += sum_n x*e
// grid 1024 (b * 128 tiles of 512 px), 256 threads, 2 px/thread (float2).
__global__ __launch_bounds__(256) void k1(const float* __restrict__ x, const float* __restrict__ Wk,
                                          float* __restrict__ ws) {
  __shared__ float zred[4];
  __shared__ float cpart[4][64];
  int blk = blockIdx.x;
  int b = blk >> 7;
  int base = (blk & 127) << 9;
  int t = threadIdx.x;
  int lane = t & 63, wid = t >> 6;
  const float* xb = x + (size_t)b * Cn * HWn;
  int n0 = base + t * 2;

  float2 xv[64];
  float kx = 0.f, ky = 0.f;
#pragma unroll
  for (int c = 0; c < Cn; ++c) {
    xv[c] = *(const float2*)(xb + (size_t)c * HWn + n0);
    float w = Wk[c];
    kx += w * xv[c].x; ky += w * xv[c].y;
  }
  float ex = __expf(kx), ey = __expf(ky);

  // Z partial
  float part = ex + ey;
#pragma unroll
  for (int off = 32; off; off >>= 1) part += __shfl_down(part, off, 64);
  if (lane == 0) zred[wid] = part;

  // per-channel partials, in-register (x NOT re-read)
#pragma unroll
  for (int c = 0; c < Cn; ++c) {
    float pc = xv[c].x * ex + xv[c].y * ey;
#pragma unroll
    for (int off = 32; off; off >>= 1) pc += __shfl_down(pc, off, 64);
    if (lane == 0) cpart[wid][c] = pc;
  }
  __syncthreads();
  if (t == 0) atomicAdd(&ws[WS_Z + b], zred[0] + zred[1] + zred[2] + zred[3]);
  if (t < 64) {
    float s = cpart[0][t] + cpart[1][t] + cpart[2][t] + cpart[3][t];
    atomicAdd(&ws[WS_XPOOL + b * 64 + t], s);
  }
}

// K2a: per-batch a = softmax(Wup @ Wq @ (xpool/Z)); wa = Wq^T a
// grid 8 (one block per batch), 64 threads, fully unrolled dot products
__global__ void k2a(const float* __restrict__ Wq, const float* __restrict__ Wup, float* __restrict__ ws) {
  int b = blockIdx.x;
  int t = threadIdx.x;  // 0..63
  __shared__ float xp_s[64], t1[64], a_s[64];
  float Zb = ws[WS_Z + b];
  xp_s[t] = ws[WS_XPOOL + b * 64 + t] / Zb;
  __syncthreads();
  float acc = 0.f;
#pragma unroll
  for (int i = 0; i < 64; ++i) acc += Wq[t * 64 + i] * xp_s[i];
  t1[t] = acc;
  __syncthreads();
  float acc2 = 0.f;
#pragma unroll
  for (int i = 0; i < 64; ++i) acc2 += Wup[t * 64 + i] * t1[i];
  float m = acc2;
#pragma unroll
  for (int off = 32; off; off >>= 1) m = fmaxf(m, __shfl_xor(m, off, 64));
  float e = __expf(acc2 - m);
  float ssum = e;
#pragma unroll
  for (int off = 32; off; off >>= 1) ssum += __shfl_xor(ssum, off, 64);
  float av = e / ssum;
  ws[WS_A + b * 64 + t] = av;
  a_s[t] = av;
  __syncthreads();
  float wav = 0.f;
#pragma unroll
  for (int o = 0; o < 64; ++o) wav += a_s[o] * Wq[o * 64 + t];
  ws[WS_WA + b * 64 + t] = wav;
}

// K2b: block 0 -> M1 = Wout@Wv_spa ; block j=1..8 -> M2[b=j-1] = Wout@diag(a[b])@Wv_spe
// Stores TRANSPOSED: dst[c*64+o] = M[o][c]
__global__ __launch_bounds__(256) void k2b(const float* __restrict__ Wout, const float* __restrict__ Wv_spa,
                                           const float* __restrict__ Wv_spe, float* __restrict__ ws) {
  __shared__ float A[4096], Bm[4096];
  int j = blockIdx.x;
  for (int idx = threadIdx.x; idx < 4096; idx += 256) {
    A[idx] = Wout[idx];
    if (j == 0)
      Bm[idx] = Wv_spa[idx];
    else
      Bm[idx] = ws[WS_A + (j - 1) * 64 + (idx >> 6)] * Wv_spe[idx];
  }
  __syncthreads();
  float* dst = (j == 0) ? (ws + WS_M1) : (ws + WS_M2 + (size_t)(j - 1) * 4096);
  for (int oi = threadIdx.x; oi < 4096; oi += 256) {
    int o = oi >> 6, i = oi & 63;
    float acc = 0.f;
#pragma unroll
    for (int c = 0; c < 64; ++c) acc += A[o * 64 + c] * Bm[c * 64 + i];
    dst[i * 64 + o] = acc;   // transposed store: [input c][output o]
  }
}

// K3 chunked full-occupancy: partial attn_spa over 16 channels -> plane(b, 2+chunk).
// grid 2048 = band(b x chunk: 32) x tile-run; 8 blocks/CU -> 32 waves/CU.
// XCD-grouping: within a band, XCD k owns tiles [k*8, k*8+8) (compact address window).
__global__ __launch_bounds__(256) void k3(const float* __restrict__ x, const float* __restrict__ ws,
                                          float* __restrict__ out) {
  int blk = blockIdx.x;
  int xcd = blk & 7;
  int q = blk >> 3;          // 0..255
  int band = q >> 3;         // 0..31 = (b, chunk)
  int tg = q & 7;            // 0..7
  int b = band >> 2;
  int chunk = band & 3;
  int tile = xcd * 8 + tg;   // 0..63
  int n0 = (tile << 10) + threadIdx.x * 4;
  const float* xb = x + ((size_t)b * Cn + chunk * 16) * HWn;
  const float* wa = ws + WS_WA + b * 64 + chunk * 16;
  float kx = 0.f, ky = 0.f, kz = 0.f, kw = 0.f;
#pragma unroll
  for (int c = 0; c < 16; ++c) {
    float4 xv = *(const float4*)(xb + (size_t)c * HWn + n0);
    float w = wa[c];
    kx += w * xv.x; ky += w * xv.y; kz += w * xv.z; kw += w * xv.w;
  }
  float4 r = {kx, ky, kz, kw};
  *(float4*)(out + ((size_t)(b * Cn + 2 + chunk)) * HWn + n0) = r;
}

// Kconv: s = sigmoid(conv7x7(attn_spa)); attn_spa = sum of planes (b,2..5)
// (k3 chunked partials), write dst_base + b*dst_stride
__global__ __launch_bounds__(256) void kconv(const float* __restrict__ Wn, const float* __restrict__ out,
                                             float* __restrict__ dst_base, size_t dst_stride) {
  __shared__ float t[38 * 38];
  int blk = blockIdx.x;
  int b = blk >> 6, ty = (blk >> 3) & 7, tx = blk & 7;
  const float* src0 = out + ((size_t)(b * Cn + 2)) * HWn;
  const float* src1 = out + ((size_t)(b * Cn + 3)) * HWn;
  const float* src2 = out + ((size_t)(b * Cn + 4)) * HWn;
  const float* src3 = out + ((size_t)(b * Cn + 5)) * HWn;
  float* dstp = dst_base + (size_t)b * dst_stride;
  for (int idx = threadIdx.x; idx < 38 * 38; idx += 256) {
    int ly = idx / 38, lx = idx - ly * 38;
    int gy = ty * 32 + ly - 3, gx = tx * 32 + lx - 3;
    float v = 0.f;
    if (gy >= 0 && gy < 256 && gx >= 0 && gx < 256) {
      int g = gy * 256 + gx;
      v = src0[g] + src1[g] + src2[g] + src3[g];
    }
    t[idx] = v;
  }
  __syncthreads();
#pragma unroll
  for (int q = 0; q < 4; ++q) {
    int pix = threadIdx.x + q * 256;
    int r = pix >> 5, col = pix & 31;
    float acc = 0.f;
#pragma unroll
    for (int dy = 0; dy < 7; ++dy)
#pragma unroll
      for (int dx = 0; dx < 7; ++dx)
        acc += t[(r + dy) * 38 + (col + dx)] * Wn[dy * 7 + dx];
    float sg = 1.f / (1.f + __expf(-acc));
    dstp[(ty * 32 + r) * 256 + tx * 32 + col] = sg;
  }
}

// K4 fast (VERIFIED 137us config — do not restructure): grid 2048, XCD-group swizzle
// (4 oc-blocks of one (b,tile) share an XCD's L2). Weights wave-uniform -> scalar
// loads (SGPR); compiler keeps acc in AGPRs (unified RF). Plain float4 stores.
__global__ __launch_bounds__(256, 4) void k4f(const float* __restrict__ x, const float* __restrict__ ws,
                                              float* __restrict__ out) {
  int d = blockIdx.x;
  int xcd = d & 7;
  int j = d >> 3;          // 0..255
  int oc = j & 3;
  int pg = j >> 2;         // 0..63
  int p = pg * 8 + xcd;    // 0..511 = (b,tile), bijective
  int b = p >> 6;
  int tile = p & 63;
  int t = threadIdx.x;
  const float* m1t = ws + WS_M1 + oc * 16;                      // [c][o] rows of 64
  const float* m2t = ws + WS_M2 + (size_t)b * 4096 + oc * 16;

  int n0 = (tile << 10) + t * 4;
  const float* xb = x + (size_t)b * Cn * HWn;
  float4 s4 = *(const float4*)(ws + WS_S + (size_t)b * HWn + n0);
  float4 acc[16];
#pragma unroll
  for (int o = 0; o < 16; ++o) acc[o] = make_float4(0.f, 0.f, 0.f, 0.f);

#pragma unroll 4
  for (int i = 0; i < 64; ++i) {
    float4 xv = *(const float4*)(xb + (size_t)i * HWn + n0);
    float4 sx;
    sx.x = s4.x * xv.x; sx.y = s4.y * xv.y; sx.z = s4.z * xv.z; sx.w = s4.w * xv.w;
    const float* w1r = m1t + i * 64;   // uniform address -> s_load
    const float* w2r = m2t + i * 64;
#pragma unroll
    for (int o = 0; o < 16; ++o) {
      float w1 = w1r[o], w2 = w2r[o];
      acc[o].x += w1 * sx.x + w2 * xv.x;
      acc[o].y += w1 * sx.y + w2 * xv.y;
      acc[o].z += w1 * sx.z + w2 * xv.z;
      acc[o].w += w1 * sx.w + w2 * xv.w;
    }
  }
  float* op = out + ((size_t)(b * Cn + oc * 16)) * HWn + n0;
#pragma unroll
  for (int o = 0; o < 16; ++o)
    *(float4*)(op + (size_t)o * HWn) = acc[o];
}

// K4 mono fallback (ws too small for s buffer): oc loop in-block, s owner-read from plane(b,0)
// (M1/M2 arrive transposed [c][o]; LDS layout [c][o] with padded stride.)
#define MSTRIDE 68
__global__ __launch_bounds__(256) void k4m(const float* __restrict__ x, const float* __restrict__ ws,
                                           float* out) {
  __shared__ float M1T[64 * MSTRIDE];
  __shared__ float M2T[64 * MSTRIDE];
  int blk = blockIdx.x;
  int b = blk >> 6;
  int base = (blk & 63) << 10;
  int t = threadIdx.x;
  const float* m1g = ws + WS_M1;
  const float* m2g = ws + WS_M2 + (size_t)b * 4096;
  for (int idx = t; idx < 4096; idx += 256) {
    int c = idx >> 6, o = idx & 63;
    M1T[c * MSTRIDE + o] = m1g[idx];
    M2T[c * MSTRIDE + o] = m2g[idx];
  }
  __syncthreads();
  int n0 = base + t * 4;
  const float* xb = x + (size_t)b * Cn * HWn;
  float* op = out + ((size_t)(b * Cn)) * HWn + n0;
  float4 s4 = *(const float4*)op;
#pragma unroll
  for (int oc = 0; oc < 4; ++oc) {
    float4 acc[16];
#pragma unroll
    for (int o = 0; o < 16; ++o) acc[o] = make_float4(0.f, 0.f, 0.f, 0.f);
    for (int i = 0; i < 64; ++i) {
      float4 xv = *(const float4*)(xb + (size_t)i * HWn + n0);
      float4 sx;
      sx.x = s4.x * xv.x; sx.y = s4.y * xv.y; sx.z = s4.z * xv.z; sx.w = s4.w * xv.w;
      const float* m1r = M1T + i * MSTRIDE + oc * 16;
      const float* m2r = M2T + i * MSTRIDE + oc * 16;
#pragma unroll
      for (int o = 0; o < 16; ++o) {
        float m1 = m1r[o], m2 = m2r[o];
        acc[o].x += m1 * sx.x + m2 * xv.x;
        acc[o].y += m1 * sx.y + m2 * xv.y;
        acc[o].z += m1 * sx.z + m2 * xv.z;
        acc[o].w += m1 * sx.w + m2 * xv.w;
      }
    }
#pragma unroll
    for (int o = 0; o < 16; ++o)
      *(float4*)(op + (size_t)(oc * 16 + o) * HWn) = acc[o];
  }
}

extern "C" void kernel_launch(void* const* d_in, const int* in_sizes, int n_in,
                              void* d_out, int out_size, void* d_ws, size_t ws_size,
                              hipStream_t stream) {
  const float* x      = (const float*)d_in[0];
  const float* Wq     = (const float*)d_in[1];
  const float* Wk     = (const float*)d_in[2];
  const float* Wv_spe = (const float*)d_in[3];
  const float* Wv_spa = (const float*)d_in[4];
  const float* Wup    = (const float*)d_in[5];
  const float* Wout   = (const float*)d_in[6];
  const float* Wn     = (const float*)d_in[7];
  float* out = (float*)d_out;
  float* ws  = (float*)d_ws;

  bool fast = ws_size >= (size_t)(WS_S + Bn * HWn) * sizeof(float);

  (void)hipMemsetAsync(ws, 0, 520 * sizeof(float), stream);  // Z + xpool accumulators
  k1<<<1024, 256, 0, stream>>>(x, Wk, ws);
  k2a<<<8, 64, 0, stream>>>(Wq, Wup, ws);
  k2b<<<9, 256, 0, stream>>>(Wout, Wv_spa, Wv_spe, ws);
  k3<<<2048, 256, 0, stream>>>(x, ws, out);
  if (fast) {
    kconv<<<512, 256, 0, stream>>>(Wn, out, ws + WS_S, (size_t)HWn);
    k4f<<<2048, 256, 0, stream>>>(x, ws, out);
  } else {
    kconv<<<512, 256, 0, stream>>>(Wn, out, out, (size_t)Cn * HWn);
    k4m<<<512, 256, 0, stream>>>(x, ws, out);
  }
}

// Round 10
// 412.544 us; speedup vs baseline: 1.0113x; 1.0084x over previous
//
#include <hip/hip_runtime.h>
#include <cstdint>
#include <cstddef>

#define Bn 8
#define Cn 64
#define HWn 65536

// ws float offsets
#define WS_Z 0
#define WS_XPOOL 8
#define WS_A 520
#define WS_WA 1032
#define WS_M1 1544
#define WS_M2 5640
#define WS_S 38408   // 8*65536 floats; 16B aligned (38408%4==0)

// NOTE: M1/M2 in ws are stored TRANSPOSED: element [c][o] at dst[c*64+o].
//
// k4f LESSONS (R3-R5, do not retry): explicit pipeline/(256,3) -> scratch spill;
// nontemporal via address-taken acc -> scratch. Golden: scalar SGPR weights,
// unroll 4, (256,4), plain float4 stores -> 137us.
//
// Streaming-wall log: k1/k3/k4f all cap at ~1.0-1.5 TB/s HBM-side, flat across
// float2/float4, unroll 16/32, 2/4/8 blocks/CU, XCD grouping (R1-R9).
// R10 theory: all channel planes are 2^18-aligned and all blocks walk c=0..63 in
// lockstep -> chip-wide DRAM channel congruence. Fix under test: per-block channel
// rotation c=(i+rot)&63 (pure reassociation). Null => declare measured roofline.

// K1 single-pass: e = exp(Wk.x); Z[b] += sum(e); xpool[b,c] += sum_n x*e
// grid 1024 (b * 128 tiles of 512 px), 256 threads, 2 px/thread (float2).
__global__ __launch_bounds__(256) void k1(const float* __restrict__ x, const float* __restrict__ Wk,
                                          float* __restrict__ ws) {
  __shared__ float zred[4];
  __shared__ float cpart[4][64];
  int blk = blockIdx.x;
  int b = blk >> 7;
  int base = (blk & 127) << 9;
  int t = threadIdx.x;
  int lane = t & 63, wid = t >> 6;
  int rot = (blk * 11) & 63;   // channel-phase decorrelation across blocks
  const float* xb = x + (size_t)b * Cn * HWn;
  int n0 = base + t * 2;

  float2 xv[64];
  float kx = 0.f, ky = 0.f;
#pragma unroll
  for (int i = 0; i < Cn; ++i) {
    int c = (i + rot) & 63;
    xv[i] = *(const float2*)(xb + (size_t)c * HWn + n0);
    float w = Wk[c];
    kx += w * xv[i].x; ky += w * xv[i].y;
  }
  float ex = __expf(kx), ey = __expf(ky);

  // Z partial
  float part = ex + ey;
#pragma unroll
  for (int off = 32; off; off >>= 1) part += __shfl_down(part, off, 64);
  if (lane == 0) zred[wid] = part;

  // per-channel partials, in-register (x NOT re-read)
#pragma unroll
  for (int i = 0; i < Cn; ++i) {
    int c = (i + rot) & 63;
    float pc = xv[i].x * ex + xv[i].y * ey;
#pragma unroll
    for (int off = 32; off; off >>= 1) pc += __shfl_down(pc, off, 64);
    if (lane == 0) cpart[wid][c] = pc;
  }
  __syncthreads();
  if (t == 0) atomicAdd(&ws[WS_Z + b], zred[0] + zred[1] + zred[2] + zred[3]);
  if (t < 64) {
    float s = cpart[0][t] + cpart[1][t] + cpart[2][t] + cpart[3][t];
    atomicAdd(&ws[WS_XPOOL + b * 64 + t], s);
  }
}

// K2a: per-batch a = softmax(Wup @ Wq @ (xpool/Z)); wa = Wq^T a
__global__ void k2a(const float* __restrict__ Wq, const float* __restrict__ Wup, float* __restrict__ ws) {
  int b = blockIdx.x;
  int t = threadIdx.x;  // 0..63
  __shared__ float xp_s[64], t1[64], a_s[64];
  float Zb = ws[WS_Z + b];
  xp_s[t] = ws[WS_XPOOL + b * 64 + t] / Zb;
  __syncthreads();
  float acc = 0.f;
#pragma unroll
  for (int i = 0; i < 64; ++i) acc += Wq[t * 64 + i] * xp_s[i];
  t1[t] = acc;
  __syncthreads();
  float acc2 = 0.f;
#pragma unroll
  for (int i = 0; i < 64; ++i) acc2 += Wup[t * 64 + i] * t1[i];
  float m = acc2;
#pragma unroll
  for (int off = 32; off; off >>= 1) m = fmaxf(m, __shfl_xor(m, off, 64));
  float e = __expf(acc2 - m);
  float ssum = e;
#pragma unroll
  for (int off = 32; off; off >>= 1) ssum += __shfl_xor(ssum, off, 64);
  float av = e / ssum;
  ws[WS_A + b * 64 + t] = av;
  a_s[t] = av;
  __syncthreads();
  float wav = 0.f;
#pragma unroll
  for (int o = 0; o < 64; ++o) wav += a_s[o] * Wq[o * 64 + t];
  ws[WS_WA + b * 64 + t] = wav;
}

// K2b: block 0 -> M1 = Wout@Wv_spa ; block j=1..8 -> M2[b=j-1] = Wout@diag(a[b])@Wv_spe
// Stores TRANSPOSED: dst[c*64+o] = M[o][c]
__global__ __launch_bounds__(256) void k2b(const float* __restrict__ Wout, const float* __restrict__ Wv_spa,
                                           const float* __restrict__ Wv_spe, float* __restrict__ ws) {
  __shared__ float A[4096], Bm[4096];
  int j = blockIdx.x;
  for (int idx = threadIdx.x; idx < 4096; idx += 256) {
    A[idx] = Wout[idx];
    if (j == 0)
      Bm[idx] = Wv_spa[idx];
    else
      Bm[idx] = ws[WS_A + (j - 1) * 64 + (idx >> 6)] * Wv_spe[idx];
  }
  __syncthreads();
  float* dst = (j == 0) ? (ws + WS_M1) : (ws + WS_M2 + (size_t)(j - 1) * 4096);
  for (int oi = threadIdx.x; oi < 4096; oi += 256) {
    int o = oi >> 6, i = oi & 63;
    float acc = 0.f;
#pragma unroll
    for (int c = 0; c < 64; ++c) acc += A[o * 64 + c] * Bm[c * 64 + i];
    dst[i * 64 + o] = acc;   // transposed store: [input c][output o]
  }
}

// K3: attn_spa[b,n] = wa[b] . x[b,:,n] -> out plane(b,2); grid 512, 4 px/thread (float4)
// R7-best form + channel rotation.
__global__ __launch_bounds__(256) void k3(const float* __restrict__ x, const float* __restrict__ ws,
                                          float* __restrict__ out) {
  int blk = blockIdx.x;
  int b = blk >> 6;
  int base = (blk & 63) << 10;
  int rot = (blk * 11) & 63;
  int n0 = base + threadIdx.x * 4;
  const float* xb = x + (size_t)b * Cn * HWn;
  const float* wa = ws + WS_WA + b * 64;
  float kx = 0.f, ky = 0.f, kz = 0.f, kw = 0.f;
#pragma unroll 32
  for (int i = 0; i < Cn; ++i) {
    int c = (i + rot) & 63;
    float4 xv = *(const float4*)(xb + (size_t)c * HWn + n0);
    float w = wa[c];
    kx += w * xv.x; ky += w * xv.y; kz += w * xv.z; kw += w * xv.w;
  }
  float4 r = {kx, ky, kz, kw};
  *(float4*)(out + ((size_t)(b * Cn + 2)) * HWn + n0) = r;
}

// Kconv: s = sigmoid(conv7x7(attn_spa)); read out plane(b,2), write dst_base + b*dst_stride
__global__ __launch_bounds__(256) void kconv(const float* __restrict__ Wn, const float* __restrict__ out,
                                             float* __restrict__ dst_base, size_t dst_stride) {
  __shared__ float t[38 * 38];
  int blk = blockIdx.x;
  int b = blk >> 6, ty = (blk >> 3) & 7, tx = blk & 7;
  const float* src = out + ((size_t)(b * Cn + 2)) * HWn;
  float* dstp = dst_base + (size_t)b * dst_stride;
  for (int idx = threadIdx.x; idx < 38 * 38; idx += 256) {
    int ly = idx / 38, lx = idx - ly * 38;
    int gy = ty * 32 + ly - 3, gx = tx * 32 + lx - 3;
    float v = 0.f;
    if (gy >= 0 && gy < 256 && gx >= 0 && gx < 256) v = src[gy * 256 + gx];
    t[idx] = v;
  }
  __syncthreads();
#pragma unroll
  for (int q = 0; q < 4; ++q) {
    int pix = threadIdx.x + q * 256;
    int r = pix >> 5, col = pix & 31;
    float acc = 0.f;
#pragma unroll
    for (int dy = 0; dy < 7; ++dy)
#pragma unroll
      for (int dx = 0; dx < 7; ++dx)
        acc += t[(r + dy) * 38 + (col + dx)] * Wn[dy * 7 + dx];
    float sg = 1.f / (1.f + __expf(-acc));
    dstp[(ty * 32 + r) * 256 + tx * 32 + col] = sg;
  }
}

// K4 fast (golden structure + channel rotation): grid 2048, XCD-group swizzle.
// rot derived from p so the 4 oc-siblings of a tile stay phase-aligned (L2 dedup).
__global__ __launch_bounds__(256, 4) void k4f(const float* __restrict__ x, const float* __restrict__ ws,
                                              float* __restrict__ out) {
  int d = blockIdx.x;
  int xcd = d & 7;
  int j = d >> 3;          // 0..255
  int oc = j & 3;
  int pg = j >> 2;         // 0..63
  int p = pg * 8 + xcd;    // 0..511 = (b,tile), bijective
  int b = p >> 6;
  int tile = p & 63;
  int rot = (p * 11) & 63;
  int t = threadIdx.x;
  const float* m1t = ws + WS_M1;                                // [c][o] rows of 64
  const float* m2t = ws + WS_M2 + (size_t)b * 4096;
  int ocs = oc * 16;

  int n0 = (tile << 10) + t * 4;
  const float* xb = x + (size_t)b * Cn * HWn;
  float4 s4 = *(const float4*)(ws + WS_S + (size_t)b * HWn + n0);
  float4 acc[16];
#pragma unroll
  for (int o = 0; o < 16; ++o) acc[o] = make_float4(0.f, 0.f, 0.f, 0.f);

#pragma unroll 4
  for (int i = 0; i < 64; ++i) {
    int ii = (i + rot) & 63;
    float4 xv = *(const float4*)(xb + (size_t)ii * HWn + n0);
    float4 sx;
    sx.x = s4.x * xv.x; sx.y = s4.y * xv.y; sx.z = s4.z * xv.z; sx.w = s4.w * xv.w;
    const float* w1r = m1t + ii * 64 + ocs;   // uniform address -> s_load
    const float* w2r = m2t + ii * 64 + ocs;
#pragma unroll
    for (int o = 0; o < 16; ++o) {
      float w1 = w1r[o], w2 = w2r[o];
      acc[o].x += w1 * sx.x + w2 * xv.x;
      acc[o].y += w1 * sx.y + w2 * xv.y;
      acc[o].z += w1 * sx.z + w2 * xv.z;
      acc[o].w += w1 * sx.w + w2 * xv.w;
    }
  }
  float* op = out + ((size_t)(b * Cn + ocs)) * HWn + n0;
#pragma unroll
  for (int o = 0; o < 16; ++o)
    *(float4*)(op + (size_t)o * HWn) = acc[o];
}

// K4 mono fallback (ws too small for s buffer): oc loop in-block, s owner-read from plane(b,0)
#define MSTRIDE 68
__global__ __launch_bounds__(256) void k4m(const float* __restrict__ x, const float* __restrict__ ws,
                                           float* out) {
  __shared__ float M1T[64 * MSTRIDE];
  __shared__ float M2T[64 * MSTRIDE];
  int blk = blockIdx.x;
  int b = blk >> 6;
  int base = (blk & 63) << 10;
  int t = threadIdx.x;
  const float* m1g = ws + WS_M1;
  const float* m2g = ws + WS_M2 + (size_t)b * 4096;
  for (int idx = t; idx < 4096; idx += 256) {
    int c = idx >> 6, o = idx & 63;
    M1T[c * MSTRIDE + o] = m1g[idx];
    M2T[c * MSTRIDE + o] = m2g[idx];
  }
  __syncthreads();
  int n0 = base + t * 4;
  const float* xb = x + (size_t)b * Cn * HWn;
  float* op = out + ((size_t)(b * Cn)) * HWn + n0;
  float4 s4 = *(const float4*)op;
#pragma unroll
  for (int oc = 0; oc < 4; ++oc) {
    float4 acc[16];
#pragma unroll
    for (int o = 0; o < 16; ++o) acc[o] = make_float4(0.f, 0.f, 0.f, 0.f);
    for (int i = 0; i < 64; ++i) {
      float4 xv = *(const float4*)(xb + (size_t)i * HWn + n0);
      float4 sx;
      sx.x = s4.x * xv.x; sx.y = s4.y * xv.y; sx.z = s4.z * xv.z; sx.w = s4.w * xv.w;
      const float* m1r = M1T + i * MSTRIDE + oc * 16;
      const float* m2r = M2T + i * MSTRIDE + oc * 16;
#pragma unroll
      for (int o = 0; o < 16; ++o) {
        float m1 = m1r[o], m2 = m2r[o];
        acc[o].x += m1 * sx.x + m2 * xv.x;
        acc[o].y += m1 * sx.y + m2 * xv.y;
        acc[o].z += m1 * sx.z + m2 * xv.z;
        acc[o].w += m1 * sx.w + m2 * xv.w;
      }
    }
#pragma unroll
    for (int o = 0; o < 16; ++o)
      *(float4*)(op + (size_t)(oc * 16 + o) * HWn) = acc[o];
  }
}

extern "C" void kernel_launch(void* const* d_in, const int* in_sizes, int n_in,
                              void* d_out, int out_size, void* d_ws, size_t ws_size,
                              hipStream_t stream) {
  const float* x      = (const float*)d_in[0];
  const float* Wq     = (const float*)d_in[1];
  const float* Wk     = (const float*)d_in[2];
  const float* Wv_spe = (const float*)d_in[3];
  const float* Wv_spa = (const float*)d_in[4];
  const float* Wup    = (const float*)d_in[5];
  const float* Wout   = (const float*)d_in[6];
  const float* Wn     = (const float*)d_in[7];
  float* out = (float*)d_out;
  float* ws  = (float*)d_ws;

  bool fast = ws_size >= (size_t)(WS_S + Bn * HWn) * sizeof(float);

  (void)hipMemsetAsync(ws, 0, 520 * sizeof(float), stream);  // Z + xpool accumulators
  k1<<<1024, 256, 0, stream>>>(x, Wk, ws);
  k2a<<<8, 64, 0, stream>>>(Wq, Wup, ws);
  k2b<<<9, 256, 0, stream>>>(Wout, Wv_spa, Wv_spe, ws);
  k3<<<512, 256, 0, stream>>>(x, ws, out);
  if (fast) {
    kconv<<<512, 256, 0, stream>>>(Wn, out, ws + WS_S, (size_t)HWn);
    k4f<<<2048, 256, 0, stream>>>(x, ws, out);
  } else {
    kconv<<<512, 256, 0, stream>>>(Wn, out, out, (size_t)Cn * HWn);
    k4m<<<512, 256, 0, stream>>>(x, ws, out);
  }
}